// Round 10
// baseline (308.800 us; speedup 1.0000x reference)
//
#include <hip/hip_runtime.h>
#include <math.h>

// SOINN+ restructured, round 10:
//  k_xx / k_dist / k_build : unchanged from round 9 (k_dist validated: conflicts gone).
//  k_seq : 5 waves. wave 0 consumer; waves 1-4 producers (t mod 4), wait done[t-5].
//    Consumer patches list candidates vs last-8 winners (unseen-at-scan <= 8),
//    spec ring depth 8 holds first-10-untracked PT/Q rows (covers first-2 at t),
//    ballot-indexed spec lookup (1 dependent LDS read). Producer budget = 4
//    consumer steps/iteration -> producers can never gate the consumer.
//    All value expressions bitwise-identical -> absmax 0.

#define N_NODES 100000
#define DIM     256
#define NS      64
#define NCH     1563
#define KC      32
#define NBMW    3125
#define CAP     4096
#define KL      192
#define KLS     136
#define NSP     10           // spec entries per step
#define NPW     8            // patch window (last-8 winners)

typedef unsigned long long u64;

__device__ __forceinline__ u64 pk(float d, int i) {
  return ((u64)__float_as_uint(d) << 32) | (unsigned)i;
}
__device__ __forceinline__ u64 umin64(u64 a, u64 b) { return a < b ? a : b; }
__device__ __forceinline__ u64 umax64(u64 a, u64 b) { return a > b ? a : b; }
__device__ __forceinline__ void mrg2(u64& A0, u64& A1, u64 B0, u64 B1) {
  u64 m = umax64(A0, B0);
  A0 = umin64(A0, B0);
  A1 = umin64(umin64(A1, B1), m);
}

template <int C>
__device__ __forceinline__ u64 dpp64(u64 x) {
  unsigned lo = (unsigned)__builtin_amdgcn_update_dpp(
      (int)0xFFFFFFFF, (int)(unsigned)(x & 0xFFFFFFFFull), C, 0xF, 0xF, false);
  unsigned hi = (unsigned)__builtin_amdgcn_update_dpp(
      (int)0xFFFFFFFF, (int)(unsigned)(x >> 32), C, 0xF, 0xF, false);
  return ((u64)hi << 32) | lo;
}
template <int C>
__device__ __forceinline__ void dpp_round(u64& A0, u64& A1) {
  u64 B0 = dpp64<C>(A0);
  u64 B1 = dpp64<C>(A1);
  mrg2(A0, A1, B0, B1);
}

__global__ void k_xx(const float* __restrict__ X, float* __restrict__ XX) {
  int i = blockIdx.x, j = threadIdx.x;
  const float* xi = X + i * DIM;
  const float* xj = X + j * DIM;
  float acc = 0.f;
  for (int k = 0; k < DIM; k += 4) {
    float4 a = *(const float4*)(xi + k);
    float4 b = *(const float4*)(xj + k);
    acc += a.x * b.x + a.y * b.y + a.z * b.z + a.w * b.w;
  }
  XX[i * NS + j] = acc;
}

__global__ __launch_bounds__(256) void k_dist(const float* __restrict__ X,
                                              const float* __restrict__ V,
                                              const float* __restrict__ XX,
                                              float* __restrict__ P,
                                              float* __restrict__ PT,
                                              float* __restrict__ Q,
                                              u64* __restrict__ SUMC) {
  __shared__ float Xl[KC][68];
  __shared__ float Vl[KC][132];
  __shared__ float sq[128];
  const int tid = threadIdx.x;
  const int n0  = blockIdx.x * 128;
  const int ty  = tid >> 5;
  const int tx  = tid & 31;
  float acc[8][4];
#pragma unroll
  for (int i = 0; i < 8; i++)
#pragma unroll
    for (int u = 0; u < 4; u++) acc[i][u] = 0.f;
  float qa = 0.f;
  const int xsl = tid & 63;
  const int xkk = (tid >> 6) * 8;
  const int vn  = tid & 127;
  const int vkk = (tid >> 7) * 16;
  const bool vok = (n0 + vn < N_NODES);
  const float* vrow = V + (size_t)(n0 + vn) * DIM + vkk;
  const float* xrow = X + xsl * DIM + xkk;

  float4 xr0, xr1, vr[4];
  xr0 = *(const float4*)(xrow + 0);
  xr1 = *(const float4*)(xrow + 4);
#pragma unroll
  for (int m = 0; m < 4; m++)
    vr[m] = vok ? *(const float4*)(vrow + 4 * m) : make_float4(0.f, 0.f, 0.f, 0.f);

  for (int c = 0; c < 8; c++) {
    __syncthreads();
    Xl[xkk + 0][xsl] = xr0.x; Xl[xkk + 1][xsl] = xr0.y;
    Xl[xkk + 2][xsl] = xr0.z; Xl[xkk + 3][xsl] = xr0.w;
    Xl[xkk + 4][xsl] = xr1.x; Xl[xkk + 5][xsl] = xr1.y;
    Xl[xkk + 6][xsl] = xr1.z; Xl[xkk + 7][xsl] = xr1.w;
#pragma unroll
    for (int m = 0; m < 4; m++) {
      Vl[vkk + 4 * m + 0][vn] = vr[m].x; Vl[vkk + 4 * m + 1][vn] = vr[m].y;
      Vl[vkk + 4 * m + 2][vn] = vr[m].z; Vl[vkk + 4 * m + 3][vn] = vr[m].w;
    }
    __syncthreads();
    if (c + 1 < 8) {
      int kc = (c + 1) * KC;
      xr0 = *(const float4*)(xrow + kc);
      xr1 = *(const float4*)(xrow + kc + 4);
#pragma unroll
      for (int m = 0; m < 4; m++)
        vr[m] = vok ? *(const float4*)(vrow + kc + 4 * m)
                    : make_float4(0.f, 0.f, 0.f, 0.f);
    }
    if (tid < 128) {
      float qq = 0.f;
#pragma unroll 8
      for (int k = 0; k < KC; k++) { float t = Vl[k][tid]; qq += t * t; }
      qa += qq;
    }
#pragma unroll 4
    for (int k = 0; k < KC; k++) {
      float xs[8], vs[4];
      *(float4*)&xs[0] = *(const float4*)&Xl[k][ty * 8];
      *(float4*)&xs[4] = *(const float4*)&Xl[k][ty * 8 + 4];
      *(float4*)&vs[0] = *(const float4*)&Vl[k][tx * 4];
#pragma unroll
      for (int i = 0; i < 8; i++)
#pragma unroll
        for (int u = 0; u < 4; u++) acc[i][u] += xs[i] * vs[u];
    }
  }
  if (tid < 128) sq[tid] = qa;
  __syncthreads();
  if (tid < 128 && n0 + tid < N_NODES) Q[n0 + tid] = qa;
  float qs[4];
  *(float4*)&qs[0] = *(const float4*)&sq[tx * 4];
  const bool full = (n0 + 128) <= N_NODES;
#pragma unroll
  for (int i = 0; i < 8; i++) {
    int s = ty * 8 + i;
    float xn = XX[s * NS + s];
#pragma unroll
    for (int u = 0; u < 4; u++) acc[i][u] = xn - 2.f * acc[i][u] + qs[u];
    float* prow = P + (size_t)s * N_NODES + n0 + tx * 4;
    if (full) {
      *(float4*)(prow) = make_float4(acc[i][0], acc[i][1], acc[i][2], acc[i][3]);
    } else {
#pragma unroll
      for (int u = 0; u < 4; u++) {
        int n = n0 + tx * 4 + u;
        if (n < N_NODES) prow[u] = acc[i][u];
      }
    }
  }
#pragma unroll
  for (int u = 0; u < 4; u++) {
    int n = n0 + tx * 4 + u;
    if (n < N_NODES) {
      float* pt = PT + (size_t)n * NS + ty * 8;
      *(float4*)(pt)     = make_float4(acc[0][u], acc[1][u], acc[2][u], acc[3][u]);
      *(float4*)(pt + 4) = make_float4(acc[4][u], acc[5][u], acc[6][u], acc[7][u]);
    }
  }
#pragma unroll
  for (int i = 0; i < 8; i++) {
    int s = ty * 8 + i;
    u64 key = ~0ull;
#pragma unroll
    for (int u = 0; u < 4; u++) {
      int n = n0 + tx * 4 + u;
      if (n < N_NODES) key = umin64(key, pk(acc[i][u], n));
    }
#pragma unroll
    for (int off = 1; off <= 8; off <<= 1)
      key = umin64(key, (u64)__shfl_xor((unsigned long long)key, off, 64));
    if ((tx & 15) == 0) {
      int chunk = (n0 >> 6) + (tx >> 4);
      if (chunk < NCH) SUMC[(size_t)s * NCH + chunk] = key;
    }
  }
}

// fused threshold + collect + sort: one block per sample
__global__ __launch_bounds__(1024) void k_build(const u64* __restrict__ SUMC,
                                                const float* __restrict__ P,
                                                u64* __restrict__ L) {
  __shared__ u64 A[CAP];
  __shared__ u64 Twave[16];
  __shared__ float Tsh;
  __shared__ int cnt;
  const int j = blockIdx.x, tid = threadIdx.x;
  const int w = tid >> 6, l = tid & 63;
  {
    int base = w * 98;
    u64 v0 = (base + l < NCH) ? SUMC[(size_t)j * NCH + base + l] : ~0ull;
    u64 v1 = (l < 34 && base + 64 + l < NCH)
                 ? SUMC[(size_t)j * NCH + base + 64 + l] : ~0ull;
    u64 s9 = ~0ull;
#pragma unroll
    for (int r = 0; r < 9; r++) {
      u64 m = umin64(v0, v1);
#pragma unroll
      for (int off = 1; off <= 32; off <<= 1)
        m = umin64(m, (u64)__shfl_xor((unsigned long long)m, off, 64));
      if (r == 8) { s9 = m; } else {
        if (v0 == m) v0 = ~0ull;
        if (v1 == m) v1 = ~0ull;
      }
    }
    if (l == 0) Twave[w] = s9;
  }
  __syncthreads();
  if (tid == 0) {
    u64 t = 0;
    for (int i = 0; i < 16; i++) t = umax64(t, Twave[i]);
    Tsh = __uint_as_float((unsigned)(t >> 32));
    cnt = 0;
  }
  __syncthreads();
  const float T = Tsh;
  const float* prow = P + (size_t)j * N_NODES;
  for (int n0 = tid * 4; n0 < N_NODES + 3; n0 += 4096) {
    float d[4];
    if (n0 + 3 < N_NODES) {
      float4 p = *(const float4*)(prow + n0);
      d[0] = p.x; d[1] = p.y; d[2] = p.z; d[3] = p.w;
    } else {
#pragma unroll
      for (int e = 0; e < 4; e++)
        d[e] = (n0 + e < N_NODES) ? prow[n0 + e] : INFINITY;
    }
#pragma unroll
    for (int e = 0; e < 4; e++) {
      if (d[e] <= T) {
        int pos = atomicAdd(&cnt, 1);
        if (pos < CAP) A[pos] = pk(d[e], n0 + e);
      }
    }
  }
  __syncthreads();
  int n = cnt; if (n > CAP) n = CAP;
  int M = 256; while (M < n) M <<= 1;
  for (int i = tid; i < M; i += 1024)
    if (i >= n) A[i] = ~0ull;
  __syncthreads();
  for (int k = 2; k <= M; k <<= 1)
    for (int s2 = k >> 1; s2 > 0; s2 >>= 1) {
      for (int i = tid; i < M; i += 1024) {
        int p = i ^ s2;
        if (p > i) {
          u64 a = A[i], b = A[p];
          bool up = ((i & k) == 0);
          if ((a > b) == up) { A[i] = b; A[p] = a; }
        }
      }
      __syncthreads();
    }
  for (int i = tid; i < KLS; i += 1024) L[(size_t)j * KL + i] = A[i];
}

__global__ __launch_bounds__(320) void k_seq(
    const float* __restrict__ PT, const float* __restrict__ Q,
    const float* __restrict__ XXg, const u64* __restrict__ L,
    const int* __restrict__ itp, float* __restrict__ out) {
  __shared__ float XXl[NS * 65];           // 16640
  __shared__ float g[128][65];             // 33280
  __shared__ float qv[128];
  __shared__ unsigned int bitmap[NBMW];    // 12500
  __shared__ int tracked[128];
  __shared__ u64 cand16[NS][16];           // 8192
  __shared__ float specg[8][NSP][NS];      // 20480: ring depth 8 >= slack 5
  __shared__ float specq[8][NSP];
  __shared__ int   specid[8][NSP];
  __shared__ int ready[NS];
  __shared__ int done[NS];

  const int tid = threadIdx.x;             // 320 = 5 waves
  const int wv = tid >> 6;
  const int lane = tid & 63;

  for (int i = tid; i < NS * NS; i += 320) {
    int r = i >> 6, c = i & 63;
    XXl[r * 65 + c] = XXg[i];
  }
  for (int i = tid; i < NBMW; i += 320) bitmap[i] = 0u;
  for (int i = tid; i < NS; i += 320) { ready[i] = 0; done[i] = 0; }
  __syncthreads();

  const int it = itp[0];
  const float eps_b = 1.0f / (float)(it + 2);
  const float eps_n = 1.0f / (float)((it + 1) * 100);
  const float xdl = XXl[lane * 65 + lane];

  if (wv == 0) {
    // ================= consumer: pure LDS + VALU =================
    int ns = 0;
    int pw[NPW];
#pragma unroll
    for (int s = 0; s < NPW; s++) pw[s] = -1;
    for (int j = 0; j < NS; j++) {
      while (__hip_atomic_load(&ready[j], __ATOMIC_ACQUIRE,
                               __HIP_MEMORY_SCOPE_WORKGROUP) == 0)
        __builtin_amdgcn_s_sleep(1);
      const int sb = j & 7;
      u64 ck = (lane < 16) ? cand16[j][lane] : ~0ull;
      int sidl = (lane < NSP) ? specid[sb][lane] : -2;
      float gA = g[lane][j], gB = g[lane + 64][j];
      float qvA = qv[lane],  qvB = qv[lane + 64];
      int   tA = tracked[lane], tB = tracked[lane + 64];
      float xrow = XXl[j * 65 + lane];
      float xnj  = XXl[j * 65 + j];
      // candidate: compacted untracked list entry, patched vs last-8 winners
      u64 A0 = ~0ull, A1 = ~0ull;
      {
        int id = (int)(unsigned)(ck & 0xFFFFFFFFull);
        bool ok = (ck != ~0ull);
#pragma unroll
        for (int s = 0; s < NPW; s++) ok = ok && (id != pw[s]);
        if (ok) { A0 = ck; }
      }
      // tracked algebraic distances (expression preserved)
      if (lane < ns)      { float d = xnj - 2.f * gA + qvA; mrg2(A0, A1, pk(d, tA), ~0ull); }
      if (lane + 64 < ns) { float d = xnj - 2.f * gB + qvB; mrg2(A0, A1, pk(d, tB), ~0ull); }
      // DPP min-2 -> exact top-2 in lane 63
      dpp_round<0x111>(A0, A1);
      dpp_round<0x112>(A0, A1);
      dpp_round<0x114>(A0, A1);
      dpp_round<0x118>(A0, A1);
      dpp_round<0x142>(A0, A1);
      dpp_round<0x143>(A0, A1);
      const int r0 = (int)(unsigned)__builtin_amdgcn_readlane(
          (int)(unsigned)(A0 & 0xFFFFFFFFull), 63);
      const int r1 = (int)(unsigned)__builtin_amdgcn_readlane(
          (int)(unsigned)(A1 & 0xFFFFFFFFull), 63);
      if (lane == 63) {
        float2 o;
        o.x = sqrtf(fmaxf(__uint_as_float((unsigned)(A0 >> 32)), 0.f) + 1e-12f);
        o.y = sqrtf(fmaxf(__uint_as_float((unsigned)(A1 >> 32)), 0.f) + 1e-12f);
        *(float2*)(out + j * 2) = o;
      }
      // slot lookup + newness
      bool h0a = (lane < ns) && (tA == r0);
      bool h0b = (lane + 64 < ns) && (tB == r0);
      u64 mk0a = __ballot(h0a), mk0b = __ballot(h0b);
      bool new0 = (mk0a | mk0b) == 0ull;
      int sl0 = new0 ? ns
                     : (mk0a ? (__ffsll((unsigned long long)mk0a) - 1)
                             : (64 + __ffsll((unsigned long long)mk0b) - 1));
      bool h1a = (lane < ns) && (tA == r1);
      bool h1b = (lane + 64 < ns) && (tB == r1);
      u64 mk1a = __ballot(h1a), mk1b = __ballot(h1b);
      bool new1 = (mk1a | mk1b) == 0ull;
      int sl1 = new1 ? (ns + (new0 ? 1 : 0))
                     : (mk1a ? (__ffsll((unsigned long long)mk1a) - 1)
                             : (64 + __ffsll((unsigned long long)mk1b) - 1));
      // ballot-indexed spec lookup (hit guaranteed when new)
      u64 mh0 = __ballot(sidl == r0);
      u64 mh1 = __ballot(sidl == r1);
      bool hit0 = mh0 != 0ull, hit1 = mh1 != 0ull;
      int s0 = hit0 ? (__ffsll((unsigned long long)mh0) - 1) : 0;
      int s1 = hit1 ? (__ffsll((unsigned long long)mh1) - 1) : 0;
      float pv0 = specg[sb][s0][lane], qq0 = specq[sb][s0];
      float pv1 = specg[sb][s1][lane], qq1 = specq[sb][s1];
      if (new0 && !hit0) { pv0 = PT[(size_t)r0 * NS + lane]; qq0 = Q[r0]; } // never taken
      if (new1 && !hit1) { pv1 = PT[(size_t)r1 * NS + lane]; qq1 = Q[r1]; }
      float gt0 = g[sl0][lane];
      float gt1 = g[sl1][lane];
      // phase 0: r0 / eps_b
      float gold0 = new0 ? (0.5f * (xdl + qq0 - pv0)) : gt0;
      float qold0 = new0 ? qq0
                         : __uint_as_float((unsigned)__builtin_amdgcn_readlane(
                               (int)__float_as_uint(sl0 < 64 ? qvA : qvB), sl0 & 63));
      float gj0 = __uint_as_float(
          (unsigned)__builtin_amdgcn_readlane((int)__float_as_uint(gold0), j));
      g[sl0][lane] = (1.f - eps_b) * gold0 + eps_b * xrow;
      if (lane == 0) {
        float om = 1.f - eps_b;
        qv[sl0] = om * om * qold0 + 2.f * eps_b * om * gj0 + eps_b * eps_b * xnj;
        tracked[sl0] = r0;
        if (new0) bitmap[r0 >> 5] |= 1u << (r0 & 31);
      }
      // phase 1: r1 / eps_n
      float gold1 = new1 ? (0.5f * (xdl + qq1 - pv1)) : gt1;
      float qold1 = new1 ? qq1
                         : __uint_as_float((unsigned)__builtin_amdgcn_readlane(
                               (int)__float_as_uint(sl1 < 64 ? qvA : qvB), sl1 & 63));
      float gj1 = __uint_as_float(
          (unsigned)__builtin_amdgcn_readlane((int)__float_as_uint(gold1), j));
      g[sl1][lane] = (1.f - eps_n) * gold1 + eps_n * xrow;
      if (lane == 0) {
        float on = 1.f - eps_n;
        qv[sl1] = on * on * qold1 + 2.f * eps_n * on * gj1 + eps_n * eps_n * xnj;
        tracked[sl1] = r1;
        if (new1) bitmap[r1 >> 5] |= 1u << (r1 & 31);
      }
      ns += (new0 ? 1 : 0) + (new1 ? 1 : 0);
#pragma unroll
      for (int s = NPW - 1; s >= 2; s--) pw[s] = pw[s - 2];
      pw[0] = r0; pw[1] = r1;
      __hip_atomic_store(&done[j], 1, __ATOMIC_RELEASE,
                         __HIP_MEMORY_SCOPE_WORKGROUP);
    }
  } else {
    // ===== producers: wave wv handles t = wv-1 (mod 4), waits done[t-5] =====
    for (int t = wv - 1; t < NS; t += 4) {
      if (t >= 5) {
        while (__hip_atomic_load(&done[t - 5], __ATOMIC_ACQUIRE,
                                 __HIP_MEMORY_SCOPE_WORKGROUP) == 0)
          __builtin_amdgcn_s_sleep(1);
      }
      const u64* Lr = L + (size_t)t * KL;
      u64 e0 = Lr[lane], e1 = Lr[lane + 64];
      u64 e2 = (lane < 8) ? Lr[128 + lane] : ~0ull;
      int i0 = (int)(unsigned)(e0 & 0xFFFFFFFFull);
      int i1 = (int)(unsigned)(e1 & 0xFFFFFFFFull);
      int i2 = (int)(unsigned)(e2 & 0xFFFFFFFFull);
      bool t0 = (e0 == ~0ull) || ((bitmap[i0 >> 5] >> (i0 & 31)) & 1u);
      bool t1 = (e1 == ~0ull) || ((bitmap[i1 >> 5] >> (i1 & 31)) & 1u);
      bool t2 = (e2 == ~0ull) || ((bitmap[i2 >> 5] >> (i2 & 31)) & 1u);
      u64 um0 = ~__ballot(t0), um1 = ~__ballot(t1), um2 = ~__ballot(t2);
      u64 below = (1ull << lane) - 1;
      int c0n = __popcll((unsigned long long)um0);
      int c1n = __popcll((unsigned long long)um1);
      int rank0 = __popcll((unsigned long long)(um0 & below));
      int rank1 = c0n + __popcll((unsigned long long)(um1 & below));
      int rank2 = c0n + c1n + __popcll((unsigned long long)(um2 & below));
      if (!t0 && rank0 < 16) cand16[t][rank0] = e0;
      if (!t1 && rank1 < 16) cand16[t][rank1] = e1;
      if (!t2 && rank2 < 16) cand16[t][rank2] = e2;
      int U = c0n + c1n + __popcll((unsigned long long)um2);
      if (lane < 16 && lane >= U) cand16[t][lane] = ~0ull;
      // spec: first-10-untracked PT/Q (U >= 136-126 = 10 always)
      const int sb = t & 7;
      int ids[NSP];
#pragma unroll
      for (int s = 0; s < NSP; s++)
        ids[s] = (int)(unsigned)(cand16[t][s] & 0xFFFFFFFFull);
#pragma unroll
      for (int s = 0; s < NSP; s++)
        specg[sb][s][lane] = PT[(size_t)ids[s] * NS + lane];
      if (lane < NSP) {
        specid[sb][lane] = ids[lane];
        specq[sb][lane] = Q[ids[lane]];
      }
      __hip_atomic_store(&ready[t], 1, __ATOMIC_RELEASE,
                         __HIP_MEMORY_SCOPE_WORKGROUP);
    }
  }
}

extern "C" void kernel_launch(void* const* d_in, const int* in_sizes, int n_in,
                              void* d_out, int out_size, void* d_ws, size_t ws_size,
                              hipStream_t stream) {
  const float* X  = (const float*)d_in[0];  // [64,256]
  const float* V  = (const float*)d_in[1];  // [100000,256]
  const int*  itp = (const int*)d_in[3];    // scalar it
  float* out = (float*)d_out;               // [64,2]

  char* ws = (char*)d_ws;
  size_t off = 0;
  auto alloc = [&](size_t bytes) -> void* {
    size_t o = (off + 255) & ~(size_t)255;
    off = o + bytes;
    return (void*)(ws + o);
  };
  float* P    = (float*)alloc((size_t)NS * N_NODES * sizeof(float)); // 25.6 MB
  float* PT   = (float*)alloc((size_t)NS * N_NODES * sizeof(float)); // 25.6 MB
  float* Q    = (float*)alloc((size_t)N_NODES * sizeof(float));
  float* XXp  = (float*)alloc((size_t)NS * NS * sizeof(float));
  u64*   SUMC = (u64*)alloc((size_t)NS * NCH * sizeof(u64));         // 800 KB
  u64*   Lst  = (u64*)alloc((size_t)NS * KL * sizeof(u64));          // 96 KB

  k_xx   <<<NS, NS, 0, stream>>>(X, XXp);
  k_dist <<<(N_NODES + 127) / 128, 256, 0, stream>>>(X, V, XXp, P, PT, Q, SUMC);
  k_build<<<NS, 1024, 0, stream>>>(SUMC, P, Lst);
  k_seq  <<<1, 320, 0, stream>>>(PT, Q, XXp, Lst, itp, out);
}